// Round 14
// baseline (215.993 us; speedup 1.0000x reference)
//
#include <hip/hip_runtime.h>
#include <hip/hip_bf16.h>

// GNN link predictor: 2x SAGEConv(mean) + dot-product decode.
// Round 14 (= round 12 + src-range-partitioned ELL rows + 2-phase agg):
//   - fill partitions each row: src<N/2 entries at front, rest at back
//     (two cursors, no sort). deg packs {clo, chi, true_deg}.
//   - agg: 64 nodes/block -> grid fully resident; ALL blocks sweep the lo
//     half first (3.2MB fp8 working set, fits 4MB XCD L2), then the hi
//     half. Accumulators live in registers across phases.
//   - everything else = round 12 (fp8 pull-agg, fused MFMA GEMM, bf16 z).

#define NBUCK 512
#define NPB   200   // nodes per bucket
#define WI    64    // ELL width
// meta: [0..NBUCK) bucket cursors; [NBUCK] ovfA count

typedef __attribute__((ext_vector_type(2))) float f32x2;
typedef __attribute__((ext_vector_type(4))) float f32x4;
typedef __attribute__((ext_vector_type(4))) int i32x4;
typedef __attribute__((ext_vector_type(2))) unsigned int u32x2;
typedef __attribute__((ext_vector_type(4))) unsigned short u16x4;
typedef __attribute__((ext_vector_type(8))) unsigned short u16x8;
typedef __attribute__((ext_vector_type(8))) short s16x8;   // bf16 MFMA frag

__device__ inline unsigned short f2bf(float f) {
    unsigned u = __float_as_uint(f);
    u += 0x7fffu + ((u >> 16) & 1u);
    return (unsigned short)(u >> 16);
}
__device__ inline float bf2f(unsigned short h) {
    return __uint_as_float(((unsigned)h) << 16);
}
__device__ inline unsigned int pk4_fp8(float a, float b, float c, float d) {
    int w = __builtin_amdgcn_cvt_pk_fp8_f32(a, b, 0, false);
    w = __builtin_amdgcn_cvt_pk_fp8_f32(c, d, w, true);
    return (unsigned int)w;
}
__device__ inline unsigned char one_fp8(float a) {
    return (unsigned char)(__builtin_amdgcn_cvt_pk_fp8_f32(a, a, 0, false) & 0xFF);
}
__device__ inline void acc_fp8(unsigned int a, f32x2& lo, f32x2& hi) {
#if __has_builtin(__builtin_amdgcn_cvt_pk_f32_fp8)
    lo += __builtin_amdgcn_cvt_pk_f32_fp8((int)a, false);
    hi += __builtin_amdgcn_cvt_pk_f32_fp8((int)a, true);
#else
    lo.x += __builtin_amdgcn_cvt_f32_fp8((int)a, 0);
    lo.y += __builtin_amdgcn_cvt_f32_fp8((int)a, 1);
    hi.x += __builtin_amdgcn_cvt_f32_fp8((int)a, 2);
    hi.y += __builtin_amdgcn_cvt_f32_fp8((int)a, 3);
#endif
}

// gather-accumulate entries [j0, j1) of one ELL row (alignment-agnostic)
__device__ inline void sweep_fp8(const unsigned int* __restrict__ featq,
                                 const int* __restrict__ row,
                                 int j0, int j1, int l,
                                 f32x2& lo, f32x2& hi) {
    int j = j0;
    for (; j < j1 && (j & 3); ++j) {
        int s = row[j];
        acc_fp8(featq[(size_t)s * 16 + l], lo, hi);
    }
    for (; j + 8 <= j1; j += 8) {
        i32x4 sA = *(const i32x4*)(row + j);
        i32x4 sB = *(const i32x4*)(row + j + 4);
        unsigned a0 = featq[(size_t)sA.x * 16 + l];
        unsigned a1 = featq[(size_t)sA.y * 16 + l];
        unsigned a2 = featq[(size_t)sA.z * 16 + l];
        unsigned a3 = featq[(size_t)sA.w * 16 + l];
        unsigned a4 = featq[(size_t)sB.x * 16 + l];
        unsigned a5 = featq[(size_t)sB.y * 16 + l];
        unsigned a6 = featq[(size_t)sB.z * 16 + l];
        unsigned a7 = featq[(size_t)sB.w * 16 + l];
        acc_fp8(a0, lo, hi); acc_fp8(a1, lo, hi);
        acc_fp8(a2, lo, hi); acc_fp8(a3, lo, hi);
        acc_fp8(a4, lo, hi); acc_fp8(a5, lo, hi);
        acc_fp8(a6, lo, hi); acc_fp8(a7, lo, hi);
    }
    if (j + 4 <= j1) {
        i32x4 sA = *(const i32x4*)(row + j);
        unsigned a0 = featq[(size_t)sA.x * 16 + l];
        unsigned a1 = featq[(size_t)sA.y * 16 + l];
        unsigned a2 = featq[(size_t)sA.z * 16 + l];
        unsigned a3 = featq[(size_t)sA.w * 16 + l];
        acc_fp8(a0, lo, hi); acc_fp8(a1, lo, hi);
        acc_fp8(a2, lo, hi); acc_fp8(a3, lo, hi);
        j += 4;
    }
    for (; j < j1; ++j) {
        int s = row[j];
        acc_fp8(featq[(size_t)s * 16 + l], lo, hi);
    }
}

// ---- prep: weights -> bf16 [n][k]; x -> bf16 + fp8; zero meta ----
__global__ __launch_bounds__(256) void k_prep(const float* __restrict__ x,
                                              const float* __restrict__ Wl1,
                                              const float* __restrict__ Wr1,
                                              const float* __restrict__ Wl2,
                                              const float* __restrict__ Wr2,
                                              unsigned short* __restrict__ w1t,
                                              unsigned short* __restrict__ w2t,
                                              unsigned short* __restrict__ xb,
                                              unsigned int* __restrict__ xq,
                                              int* __restrict__ meta,
                                              long long nx) {
    if (blockIdx.x < 16) {  // weights: 2 x 128x128 (+ meta zero in block 0)
        if (blockIdx.x == 0) {
            i32x4 z = {0, 0, 0, 0};
            *(i32x4*)(meta + threadIdx.x * 4) = z;
        }
        int id = (blockIdx.x * 256 + threadIdx.x) * 8;  // 0..32760
        int which = id >> 14;
        int r0 = id & 16383;
#pragma unroll
        for (int i = 0; i < 8; ++i) {
            int r = r0 + i;
            int n = r >> 7, k = r & 127;
            float v;
            if (which == 0) v = (k < 64) ? Wl1[k * 128 + n] : Wr1[(k - 64) * 128 + n];
            else            v = (n < 64) ? Wl2[k * 64 + n] : Wr2[k * 64 + (n - 64)];
            (which ? w2t : w1t)[r] = f2bf(v);
        }
        return;
    }
    long long i = ((long long)(blockIdx.x - 16) * 256 + threadIdx.x) * 8;
    if (i + 8 > nx) return;
    f32x4 a = __builtin_nontemporal_load((const f32x4*)(x + i));
    f32x4 b = __builtin_nontemporal_load((const f32x4*)(x + i + 4));
    u16x8 o;
    o[0] = f2bf(a.x); o[1] = f2bf(a.y); o[2] = f2bf(a.z); o[3] = f2bf(a.w);
    o[4] = f2bf(b.x); o[5] = f2bf(b.y); o[6] = f2bf(b.z); o[7] = f2bf(b.w);
    __builtin_nontemporal_store(o, (u16x8*)(xb + i));
    u32x2 q;
    q.x = pk4_fp8(a.x, a.y, a.z, a.w);
    q.y = pk4_fp8(b.x, b.y, b.z, b.w);
    __builtin_nontemporal_store(q, (u32x2*)(xq + (i >> 2)));
}

// ---- pass A: edges -> 512 dst-range buckets (packed 4B: local<<17 | src) ----
// 512 threads x 16 edges = 8192-edge tiles (64B avg bucket runs).
__global__ __launch_bounds__(512) void k_bucket(const int* __restrict__ ei, int E,
                                                int capB,
                                                int* __restrict__ buckets,
                                                int* __restrict__ meta,
                                                int* __restrict__ ovfA) {
    __shared__ int lcnt[NBUCK];
    __shared__ int lbase[NBUCK];
    __shared__ int lidx[NBUCK];
    const int t = threadIdx.x;
    const int e0 = blockIdx.x * 8192;
    for (int i = t; i < NBUCK; i += 512) { lcnt[i] = 0; lidx[i] = 0; }
    __syncthreads();

    int s[16], d[16], b[16];
    bool v[16];
#pragma unroll
    for (int r = 0; r < 4; ++r) {
        int e = e0 + r * 2048 + t * 4;
        i32x4 s4, d4;
        if (e + 4 <= E) {
            s4 = __builtin_nontemporal_load((const i32x4*)(ei + e));
            d4 = __builtin_nontemporal_load((const i32x4*)(ei + E + e));
        } else {
            s4.x = (e < E) ? ei[e] : 0;         d4.x = (e < E) ? ei[E + e] : 0;
            s4.y = (e + 1 < E) ? ei[e + 1] : 0; d4.y = (e + 1 < E) ? ei[E + e + 1] : 0;
            s4.z = (e + 2 < E) ? ei[e + 2] : 0; d4.z = (e + 2 < E) ? ei[E + e + 2] : 0;
            s4.w = (e + 3 < E) ? ei[e + 3] : 0; d4.w = (e + 3 < E) ? ei[E + e + 3] : 0;
        }
        s[r * 4 + 0] = s4.x; s[r * 4 + 1] = s4.y; s[r * 4 + 2] = s4.z; s[r * 4 + 3] = s4.w;
        d[r * 4 + 0] = d4.x; d[r * 4 + 1] = d4.y; d[r * 4 + 2] = d4.z; d[r * 4 + 3] = d4.w;
        v[r * 4 + 0] = (e < E); v[r * 4 + 1] = (e + 1 < E);
        v[r * 4 + 2] = (e + 2 < E); v[r * 4 + 3] = (e + 3 < E);
    }
#pragma unroll
    for (int k = 0; k < 16; ++k) {
        b[k] = (unsigned)d[k] / NPB;
        if (v[k]) atomicAdd(&lcnt[b[k]], 1);
    }
    __syncthreads();
    for (int i = t; i < NBUCK; i += 512) {
        int c = lcnt[i];
        lbase[i] = (c > 0) ? atomicAdd(&meta[i], c) : 0;
    }
    __syncthreads();
#pragma unroll
    for (int k = 0; k < 16; ++k) {
        if (!v[k]) continue;
        int slot = atomicAdd(&lidx[b[k]], 1);
        int pos = lbase[b[k]] + slot;
        if (pos < capB) {
            int local = d[k] - b[k] * NPB;
            buckets[(size_t)b[k] * capB + pos] = (local << 17) | s[k];
        } else {  // statistically unreachable
            int oi = atomicAdd(&meta[NBUCK], 1);
            ovfA[(size_t)oi * 2] = s[k];
            ovfA[(size_t)oi * 2 + 1] = d[k];
        }
    }
}

// ---- pass B: one block per bucket; build src-range-partitioned ELL rows
//      in LDS (lo from front, hi from back), stream out. ----
__global__ __launch_bounds__(256) void k_fill_lds(const int* __restrict__ buckets,
                                                  int capB,
                                                  const int* __restrict__ meta_ro,
                                                  const int* __restrict__ ovfA,
                                                  int* __restrict__ deg,
                                                  int* __restrict__ ell, int N,
                                                  int half) {
    __shared__ int clo_[NPB];
    __shared__ int chi_[NPB];
    __shared__ int ells[NPB * WI];  // 200*64*4 = 51200 B
    const int t = threadIdx.x;
    const int b = blockIdx.x;
    const int base = b * NPB;
    for (int i = t; i < NPB; i += 256) { clo_[i] = 0; chi_[i] = 0; }
    __syncthreads();
    const int cnt = min(meta_ro[b], capB);
    const int* bk = buckets + (size_t)b * capB;
    for (int i = t; i < cnt; i += 256) {
        unsigned v = (unsigned)__builtin_nontemporal_load(bk + i);
        int s = (int)(v & 0x1FFFFu);
        int local = (int)(v >> 17);
        if (s < half) {
            int slot = atomicAdd(&clo_[local], 1);
            if (slot < WI) ells[local * WI + slot] = s;
        } else {
            int pos = atomicAdd(&chi_[local], 1);
            if (pos < WI) ells[local * WI + (WI - 1 - pos)] = s;
        }
    }
    // pass-A overflow edges in this block's range (normally zero)
    const int no = meta_ro[NBUCK];
    for (int i = t; i < no; i += 256) {
        int s = ovfA[(size_t)i * 2];
        int d = ovfA[(size_t)i * 2 + 1];
        if (d >= base && d < base + NPB) {
            int local = d - base;
            if (s < half) {
                int slot = atomicAdd(&clo_[local], 1);
                if (slot < WI) ells[local * WI + slot] = s;
            } else {
                int pos = atomicAdd(&chi_[local], 1);
                if (pos < WI) ells[local * WI + (WI - 1 - pos)] = s;
            }
        }
    }
    __syncthreads();
    const int nn = min(NPB, N - base);
    if (nn <= 0) return;
    for (int i = t; i < nn; i += 256) {
        int lo = clo_[i], hi = chi_[i];
        int dt = lo + hi;
        int l2 = min(lo, WI);
        int h2 = min(hi, WI - l2);
        deg[base + i] = l2 | (h2 << 8) | (min(dt, 65535) << 16);
    }
    const int lim = nn * WI;
    for (int j = t * 4; j < lim; j += 256 * 4) {
        const int row = j >> 6;
        const int jo = j & 63;
        const int lo = min(clo_[row], WI);
        const int hs = WI - min(chi_[row], WI - lo);
        if (jo < lo || jo + 4 > hs) {
            i32x4 vv = *(const i32x4*)&ells[j];
            __builtin_nontemporal_store(vv, (i32x4*)(ell + (size_t)base * WI + j));
        }
    }
}

// ---- two-phase mean aggregation over fp8 rows ----
// 64 nodes/block (grid fully resident): all blocks sweep lo-half entries
// first (L2-resident window), then hi-half. Acc in registers across phases.
__global__ __launch_bounds__(256) void k_agg_q(const unsigned int* __restrict__ featq,
                                               const int* __restrict__ deg,
                                               const int* __restrict__ ell,
                                               unsigned short* __restrict__ outb,
                                               const unsigned short* __restrict__ addend,
                                               int n) {
    const int t = threadIdx.x;
    const int g = t >> 4, l = t & 15;
    const int base = blockIdx.x * 64 + g * 4;
    f32x2 alo[4], ahi[4];
    int dw[4];
#pragma unroll
    for (int k = 0; k < 4; ++k) {
        alo[k] = f32x2{0.f, 0.f};
        ahi[k] = f32x2{0.f, 0.f};
        dw[k] = (base + k < n) ? deg[base + k] : 0;
    }
    // phase 0: lo-half entries [0, clo)
#pragma unroll
    for (int k = 0; k < 4; ++k) {
        int clo = dw[k] & 255;
        if (clo > 0)
            sweep_fp8(featq, ell + (size_t)(base + k) * WI, 0, clo, l, alo[k], ahi[k]);
    }
    // phase 1: hi-half entries [WI-chi, WI)
#pragma unroll
    for (int k = 0; k < 4; ++k) {
        int chi = (dw[k] >> 8) & 255;
        if (chi > 0)
            sweep_fp8(featq, ell + (size_t)(base + k) * WI, WI - chi, WI, l, alo[k], ahi[k]);
    }
    // finalize
#pragma unroll
    for (int k = 0; k < 4; ++k) {
        int node = base + k;
        if (node >= n) continue;
        int dt = dw[k] >> 16;
        const float inv = 1.0f / (float)max(dt, 1);
        float vx = alo[k].x * inv, vy = alo[k].y * inv;
        float vz = ahi[k].x * inv, vw = ahi[k].y * inv;
        const size_t o = (size_t)node * 64 + l * 4;
        if (addend) {
            u16x4 ad = *(const u16x4*)(addend + o);
            vx += bf2f(ad[0]); vy += bf2f(ad[1]);
            vz += bf2f(ad[2]); vw += bf2f(ad[3]);
        }
        u16x4 ob;
        ob[0] = f2bf(vx); ob[1] = f2bf(vy); ob[2] = f2bf(vz); ob[3] = f2bf(vw);
        __builtin_nontemporal_store(ob, (u16x4*)(outb + o));
    }
}

// ---- fused MFMA GEMM: h = relu([mean1b|xb]@W1+b1) in LDS;
//      pq(fp8) = h@Wl2 ; zbb(bf16) = h@Wr2+b2 ----
__global__ __launch_bounds__(256) void k_gemm_fused(
    const unsigned short* __restrict__ mean1b,  // [M][64]
    const unsigned short* __restrict__ xb,      // [M][64]
    const unsigned short* __restrict__ w1t,     // [128][128] bf16 [n][k]
    const unsigned short* __restrict__ w2t,     // [128][128] bf16 [n][k]
    const float* __restrict__ b1,
    const float* __restrict__ b2,
    unsigned int* __restrict__ pq,              // [M][16] u32 (64 fp8)
    unsigned short* __restrict__ zbb, int M) {  // [M][64] bf16
    __shared__ unsigned short W1s[128 * 128];
    __shared__ unsigned short W2s[128 * 128];
    __shared__ __align__(16) unsigned short HT[128 * 136];  // h tile, pad 8
    const int t = threadIdx.x;
    const int wv = t >> 6, l = t & 63;
    const int lr = l & 15, lq = l >> 4;
    const int wrow = wv * 32;
    const int row0 = blockIdx.x * 128 + wrow;

    const s16x8 zf = {0, 0, 0, 0, 0, 0, 0, 0};
    s16x8 af[2][4];
#pragma unroll
    for (int mt = 0; mt < 2; ++mt) {
        int r = row0 + mt * 16 + lr;
        bool ok = r < M;
#pragma unroll
        for (int ks = 0; ks < 4; ++ks) {
            int k = ks * 32 + lq * 8;
            const unsigned short* src = (k < 64) ? (mean1b + (size_t)r * 64 + k)
                                                 : (xb + (size_t)r * 64 + (k - 64));
            af[mt][ks] = ok ? *(const s16x8*)src : zf;
        }
    }
#pragma unroll
    for (int i = 0; i < 8; ++i) {
        int byte = (i * 256 + t) * 16;
        int swz = byte ^ (((byte >> 8) & 7) << 4);
        *(u16x8*)((char*)W1s + swz) = *(const u16x8*)((const char*)w1t + byte);
        *(u16x8*)((char*)W2s + swz) = *(const u16x8*)((const char*)w2t + byte);
    }
    __syncthreads();
    if (row0 >= M) return;

    // ---- layer 1 MFMA ----
    f32x4 acc[2][8];
#pragma unroll
    for (int mt = 0; mt < 2; ++mt)
#pragma unroll
        for (int nt = 0; nt < 8; ++nt) {
            f32x4 z = {0.f, 0.f, 0.f, 0.f};
            acc[mt][nt] = z;
        }
#pragma unroll
    for (int nt = 0; nt < 8; ++nt) {
        int n = nt * 16 + lr;
#pragma unroll
        for (int ks = 0; ks < 4; ++ks) {
            int byte = (n * 256 + ks * 64 + lq * 16) ^ ((n & 7) << 4);
            s16x8 bf = *(const s16x8*)((const char*)W1s + byte);
            acc[0][nt] = __builtin_amdgcn_mfma_f32_16x16x32_bf16(af[0][ks], bf, acc[0][nt], 0, 0, 0);
            acc[1][nt] = __builtin_amdgcn_mfma_f32_16x16x32_bf16(af[1][ks], bf, acc[1][nt], 0, 0, 0);
        }
    }
#pragma unroll
    for (int nt = 0; nt < 8; ++nt) {
        float bb = b1[nt * 16 + lr];
#pragma unroll
        for (int mt = 0; mt < 2; ++mt)
#pragma unroll
            for (int j = 0; j < 4; ++j) {
                float v = fmaxf(acc[mt][nt][j] + bb, 0.f);
                HT[(wrow + mt * 16 + lq * 4 + j) * 136 + nt * 16 + lr] = f2bf(v);
            }
    }
    // ---- layer 2 (A from own HT rows; no barrier needed) ----
    s16x8 af2[2][4];
#pragma unroll
    for (int mt = 0; mt < 2; ++mt)
#pragma unroll
        for (int ks = 0; ks < 4; ++ks)
            af2[mt][ks] = *(const s16x8*)&HT[(wrow + mt * 16 + lr) * 136 + ks * 32 + lq * 8];

    f32x4 acc2[2][8];
#pragma unroll
    for (int mt = 0; mt < 2; ++mt)
#pragma unroll
        for (int nt = 0; nt < 8; ++nt) {
            f32x4 z = {0.f, 0.f, 0.f, 0.f};
            acc2[mt][nt] = z;
        }
#pragma unroll
    for (int nt = 0; nt < 8; ++nt) {
        int n = nt * 16 + lr;
#pragma unroll
        for (int ks = 0; ks < 4; ++ks) {
            int byte = (n * 256 + ks * 64 + lq * 16) ^ ((n & 7) << 4);
            s16x8 bf = *(const s16x8*)((const char*)W2s + byte);
            acc2[0][nt] = __builtin_amdgcn_mfma_f32_16x16x32_bf16(af2[0][ks], bf, acc2[0][nt], 0, 0, 0);
            acc2[1][nt] = __builtin_amdgcn_mfma_f32_16x16x32_bf16(af2[1][ks], bf, acc2[1][nt], 0, 0, 0);
        }
    }
    char* scratch = (char*)&HT[(size_t)wrow * 136];  // 8704 B, wave-private
    // epilogue A: pq (cols 0..63 -> fp8) via byte stage [32][68]
    unsigned char* csb = (unsigned char*)scratch;
#pragma unroll
    for (int nt = 0; nt < 4; ++nt)
#pragma unroll
        for (int mt = 0; mt < 2; ++mt)
#pragma unroll
            for (int j = 0; j < 4; ++j)
                csb[(mt * 16 + lq * 4 + j) * 68 + nt * 16 + lr] = one_fp8(acc2[mt][nt][j]);
#pragma unroll
    for (int p = 0; p < 8; ++p) {
        int r = p * 4 + lq;
        int gr = row0 + r;
        if (gr < M) {
            unsigned int v = *(const unsigned int*)&csb[r * 68 + lr * 4];
            __builtin_nontemporal_store(v, pq + (size_t)gr * 16 + lr);
        }
    }
    __syncthreads();
    // epilogue B: zbb (cols 64..127 -> bf16, +b2) via u16 stage [32][72]
    unsigned short* csu = (unsigned short*)scratch;
#pragma unroll
    for (int nt = 4; nt < 8; ++nt) {
        int col = (nt - 4) * 16 + lr;
        float bb = b2[col];
#pragma unroll
        for (int mt = 0; mt < 2; ++mt)
#pragma unroll
            for (int j = 0; j < 4; ++j)
                csu[(mt * 16 + lq * 4 + j) * 72 + col] = f2bf(acc2[mt][nt][j] + bb);
    }
#pragma unroll
    for (int p = 0; p < 8; ++p) {
        int r = p * 4 + lq;
        int gr = row0 + r;
        if (gr < M) {
            u16x4 v = *(const u16x4*)&csu[r * 72 + lr * 4];
            __builtin_nontemporal_store(v, (u16x4*)(zbb + (size_t)gr * 64 + lr * 4));
        }
    }
}

// ---- decode over bf16 z: 16 lanes per pair; u16x4 loads; shfl reduce ----
__global__ __launch_bounds__(256) void k_decode(const unsigned short* __restrict__ zq,
                                                const int* __restrict__ eli,
                                                float* __restrict__ out, int P) {
    int t = threadIdx.x;
    int g = blockIdx.x * 16 + (t >> 4);
    int l = t & 15;
    if (g >= P) return;
    int a = __builtin_nontemporal_load(eli + g);
    int b = __builtin_nontemporal_load(eli + P + g);
    u16x4 va = *(const u16x4*)(zq + (size_t)a * 64 + l * 4);
    u16x4 vb = *(const u16x4*)(zq + (size_t)b * 64 + l * 4);
    float s = bf2f(va[0]) * bf2f(vb[0]) + bf2f(va[1]) * bf2f(vb[1])
            + bf2f(va[2]) * bf2f(vb[2]) + bf2f(va[3]) * bf2f(vb[3]);
    s += __shfl_xor(s, 1);
    s += __shfl_xor(s, 2);
    s += __shfl_xor(s, 4);
    s += __shfl_xor(s, 8);
    if (l == 0) out[g] = s;
}

extern "C" void kernel_launch(void* const* d_in, const int* in_sizes, int n_in,
                              void* d_out, int out_size, void* d_ws, size_t ws_size,
                              hipStream_t stream) {
    const float* x   = (const float*)d_in[0];
    const float* Wl1 = (const float*)d_in[1];
    const float* Wr1 = (const float*)d_in[2];
    const float* b1  = (const float*)d_in[3];
    const float* Wl2 = (const float*)d_in[4];
    const float* Wr2 = (const float*)d_in[5];
    const float* b2  = (const float*)d_in[6];
    const int* ei  = (const int*)d_in[7];
    const int* eli = (const int*)d_in[8];
    const int N = in_sizes[0] / 64;
    const int E = in_sizes[7] / 2;
    const int P = in_sizes[8] / 2;
    float* out = (float*)d_out;

    const int capB = ((E / NBUCK) * 5 / 4 + 1024 + 3) & ~3;
    const int half = N / 2;

    char* w = (char*)d_ws;
    auto alloc = [&](size_t bytes) {
        char* pp = w;
        w += (bytes + 255) & ~(size_t)255;
        return pp;
    };
    int* deg  = (int*)alloc((size_t)N * 4);
    int* meta = (int*)alloc(4096);
    int* ell  = (int*)alloc((size_t)N * WI * 4);
    unsigned short* xb     = (unsigned short*)alloc((size_t)N * 64 * 2);
    unsigned int*   xq     = (unsigned int*)alloc((size_t)N * 64);
    unsigned int*   pq     = (unsigned int*)alloc((size_t)N * 64);
    unsigned short* mean1b = (unsigned short*)alloc((size_t)N * 64 * 2);
    unsigned short* zq     = (unsigned short*)alloc((size_t)N * 64 * 2);
    unsigned short* zbb    = (unsigned short*)alloc((size_t)N * 64 * 2);
    unsigned short* w1t    = (unsigned short*)alloc(128 * 128 * 2);
    unsigned short* w2t    = (unsigned short*)alloc(128 * 128 * 2);
    int* buckets = (int*)alloc((size_t)NBUCK * capB * 4);
    int* ovfA    = (int*)alloc((size_t)E * 8);

    {
        long long n = (long long)N * 64;
        int xblocks = (int)((n / 8 + 255) / 256);
        k_prep<<<16 + xblocks, 256, 0, stream>>>(x, Wl1, Wr1, Wl2, Wr2,
                                                 w1t, w2t, xb, xq, meta, n);
    }

    k_bucket<<<(E + 8191) / 8192, 512, 0, stream>>>(ei, E, capB, buckets, meta, ovfA);
    k_fill_lds<<<(N + NPB - 1) / NPB, 256, 0, stream>>>(buckets, capB, meta, ovfA,
                                                        deg, ell, N, half);

    const int agg_grid = (N + 63) / 64;
    k_agg_q<<<agg_grid, 256, 0, stream>>>(xq, deg, ell, mean1b, nullptr, N);

    const int gemm_grid = (N + 127) / 128;
    k_gemm_fused<<<gemm_grid, 256, 0, stream>>>(mean1b, xb, w1t, w2t, b1, b2,
                                                pq, zbb, N);

    k_agg_q<<<agg_grid, 256, 0, stream>>>(pq, deg, ell, zq, zbb, N);

    k_decode<<<(P + 15) / 16, 256, 0, stream>>>(zq, eli, out, P);
}

// Round 15
// 160.085 us; speedup vs baseline: 1.3492x; 1.3492x over previous
//
#include <hip/hip_runtime.h>
#include <hip/hip_bf16.h>

// GNN link predictor: 2x SAGEConv(mean) + dot-product decode.
// Round 15 (= r14 partitioned-ELL layout + r12 agg issue shape):
//   - fill partitions each row: src<N/2 at front, rest at back (two LDS
//     cursors). deg packs {clo, chi, true_deg}.
//   - agg: 1 node per 16-lane group, 16 nodes/block, grid 6250 (r12's
//     proven issue rate); sweeps lo range then hi range -> loose device
//     phase coherence keeps a 3.2MB window L2-resident (r14: FETCH 54MB).
//   - fp8 pull-agg, fused MFMA GEMM, bf16 z decode as r12.

#define NBUCK 512
#define NPB   200   // nodes per bucket
#define WI    64    // ELL width
// meta: [0..NBUCK) bucket cursors; [NBUCK] ovfA count

typedef __attribute__((ext_vector_type(2))) float f32x2;
typedef __attribute__((ext_vector_type(4))) float f32x4;
typedef __attribute__((ext_vector_type(4))) int i32x4;
typedef __attribute__((ext_vector_type(2))) unsigned int u32x2;
typedef __attribute__((ext_vector_type(4))) unsigned short u16x4;
typedef __attribute__((ext_vector_type(8))) unsigned short u16x8;
typedef __attribute__((ext_vector_type(8))) short s16x8;   // bf16 MFMA frag

__device__ inline unsigned short f2bf(float f) {
    unsigned u = __float_as_uint(f);
    u += 0x7fffu + ((u >> 16) & 1u);
    return (unsigned short)(u >> 16);
}
__device__ inline float bf2f(unsigned short h) {
    return __uint_as_float(((unsigned)h) << 16);
}
__device__ inline unsigned int pk4_fp8(float a, float b, float c, float d) {
    int w = __builtin_amdgcn_cvt_pk_fp8_f32(a, b, 0, false);
    w = __builtin_amdgcn_cvt_pk_fp8_f32(c, d, w, true);
    return (unsigned int)w;
}
__device__ inline unsigned char one_fp8(float a) {
    return (unsigned char)(__builtin_amdgcn_cvt_pk_fp8_f32(a, a, 0, false) & 0xFF);
}
__device__ inline void acc_fp8(unsigned int a, f32x2& lo, f32x2& hi) {
#if __has_builtin(__builtin_amdgcn_cvt_pk_f32_fp8)
    lo += __builtin_amdgcn_cvt_pk_f32_fp8((int)a, false);
    hi += __builtin_amdgcn_cvt_pk_f32_fp8((int)a, true);
#else
    lo.x += __builtin_amdgcn_cvt_f32_fp8((int)a, 0);
    lo.y += __builtin_amdgcn_cvt_f32_fp8((int)a, 1);
    hi.x += __builtin_amdgcn_cvt_f32_fp8((int)a, 2);
    hi.y += __builtin_amdgcn_cvt_f32_fp8((int)a, 3);
#endif
}

// gather-accumulate entries [j0, j1) of one ELL row (alignment-agnostic)
__device__ inline void sweep_fp8(const unsigned int* __restrict__ featq,
                                 const int* __restrict__ row,
                                 int j0, int j1, int l,
                                 f32x2& lo, f32x2& hi) {
    int j = j0;
    for (; j < j1 && (j & 3); ++j) {
        int s = row[j];
        acc_fp8(featq[(size_t)s * 16 + l], lo, hi);
    }
    for (; j + 8 <= j1; j += 8) {
        i32x4 sA = *(const i32x4*)(row + j);
        i32x4 sB = *(const i32x4*)(row + j + 4);
        unsigned a0 = featq[(size_t)sA.x * 16 + l];
        unsigned a1 = featq[(size_t)sA.y * 16 + l];
        unsigned a2 = featq[(size_t)sA.z * 16 + l];
        unsigned a3 = featq[(size_t)sA.w * 16 + l];
        unsigned a4 = featq[(size_t)sB.x * 16 + l];
        unsigned a5 = featq[(size_t)sB.y * 16 + l];
        unsigned a6 = featq[(size_t)sB.z * 16 + l];
        unsigned a7 = featq[(size_t)sB.w * 16 + l];
        acc_fp8(a0, lo, hi); acc_fp8(a1, lo, hi);
        acc_fp8(a2, lo, hi); acc_fp8(a3, lo, hi);
        acc_fp8(a4, lo, hi); acc_fp8(a5, lo, hi);
        acc_fp8(a6, lo, hi); acc_fp8(a7, lo, hi);
    }
    if (j + 4 <= j1) {
        i32x4 sA = *(const i32x4*)(row + j);
        unsigned a0 = featq[(size_t)sA.x * 16 + l];
        unsigned a1 = featq[(size_t)sA.y * 16 + l];
        unsigned a2 = featq[(size_t)sA.z * 16 + l];
        unsigned a3 = featq[(size_t)sA.w * 16 + l];
        acc_fp8(a0, lo, hi); acc_fp8(a1, lo, hi);
        acc_fp8(a2, lo, hi); acc_fp8(a3, lo, hi);
        j += 4;
    }
    for (; j < j1; ++j) {
        int s = row[j];
        acc_fp8(featq[(size_t)s * 16 + l], lo, hi);
    }
}

// ---- prep: weights -> bf16 [n][k]; x -> bf16 + fp8; zero meta ----
__global__ __launch_bounds__(256) void k_prep(const float* __restrict__ x,
                                              const float* __restrict__ Wl1,
                                              const float* __restrict__ Wr1,
                                              const float* __restrict__ Wl2,
                                              const float* __restrict__ Wr2,
                                              unsigned short* __restrict__ w1t,
                                              unsigned short* __restrict__ w2t,
                                              unsigned short* __restrict__ xb,
                                              unsigned int* __restrict__ xq,
                                              int* __restrict__ meta,
                                              long long nx) {
    if (blockIdx.x < 16) {  // weights: 2 x 128x128 (+ meta zero in block 0)
        if (blockIdx.x == 0) {
            i32x4 z = {0, 0, 0, 0};
            *(i32x4*)(meta + threadIdx.x * 4) = z;
        }
        int id = (blockIdx.x * 256 + threadIdx.x) * 8;  // 0..32760
        int which = id >> 14;
        int r0 = id & 16383;
#pragma unroll
        for (int i = 0; i < 8; ++i) {
            int r = r0 + i;
            int n = r >> 7, k = r & 127;
            float v;
            if (which == 0) v = (k < 64) ? Wl1[k * 128 + n] : Wr1[(k - 64) * 128 + n];
            else            v = (n < 64) ? Wl2[k * 64 + n] : Wr2[k * 64 + (n - 64)];
            (which ? w2t : w1t)[r] = f2bf(v);
        }
        return;
    }
    long long i = ((long long)(blockIdx.x - 16) * 256 + threadIdx.x) * 8;
    if (i + 8 > nx) return;
    f32x4 a = __builtin_nontemporal_load((const f32x4*)(x + i));
    f32x4 b = __builtin_nontemporal_load((const f32x4*)(x + i + 4));
    u16x8 o;
    o[0] = f2bf(a.x); o[1] = f2bf(a.y); o[2] = f2bf(a.z); o[3] = f2bf(a.w);
    o[4] = f2bf(b.x); o[5] = f2bf(b.y); o[6] = f2bf(b.z); o[7] = f2bf(b.w);
    __builtin_nontemporal_store(o, (u16x8*)(xb + i));
    u32x2 q;
    q.x = pk4_fp8(a.x, a.y, a.z, a.w);
    q.y = pk4_fp8(b.x, b.y, b.z, b.w);
    __builtin_nontemporal_store(q, (u32x2*)(xq + (i >> 2)));
}

// ---- pass A: edges -> 512 dst-range buckets (packed 4B: local<<17 | src) ----
// 512 threads x 16 edges = 8192-edge tiles (64B avg bucket runs).
__global__ __launch_bounds__(512) void k_bucket(const int* __restrict__ ei, int E,
                                                int capB,
                                                int* __restrict__ buckets,
                                                int* __restrict__ meta,
                                                int* __restrict__ ovfA) {
    __shared__ int lcnt[NBUCK];
    __shared__ int lbase[NBUCK];
    __shared__ int lidx[NBUCK];
    const int t = threadIdx.x;
    const int e0 = blockIdx.x * 8192;
    for (int i = t; i < NBUCK; i += 512) { lcnt[i] = 0; lidx[i] = 0; }
    __syncthreads();

    int s[16], d[16], b[16];
    bool v[16];
#pragma unroll
    for (int r = 0; r < 4; ++r) {
        int e = e0 + r * 2048 + t * 4;
        i32x4 s4, d4;
        if (e + 4 <= E) {
            s4 = __builtin_nontemporal_load((const i32x4*)(ei + e));
            d4 = __builtin_nontemporal_load((const i32x4*)(ei + E + e));
        } else {
            s4.x = (e < E) ? ei[e] : 0;         d4.x = (e < E) ? ei[E + e] : 0;
            s4.y = (e + 1 < E) ? ei[e + 1] : 0; d4.y = (e + 1 < E) ? ei[E + e + 1] : 0;
            s4.z = (e + 2 < E) ? ei[e + 2] : 0; d4.z = (e + 2 < E) ? ei[E + e + 2] : 0;
            s4.w = (e + 3 < E) ? ei[e + 3] : 0; d4.w = (e + 3 < E) ? ei[E + e + 3] : 0;
        }
        s[r * 4 + 0] = s4.x; s[r * 4 + 1] = s4.y; s[r * 4 + 2] = s4.z; s[r * 4 + 3] = s4.w;
        d[r * 4 + 0] = d4.x; d[r * 4 + 1] = d4.y; d[r * 4 + 2] = d4.z; d[r * 4 + 3] = d4.w;
        v[r * 4 + 0] = (e < E); v[r * 4 + 1] = (e + 1 < E);
        v[r * 4 + 2] = (e + 2 < E); v[r * 4 + 3] = (e + 3 < E);
    }
#pragma unroll
    for (int k = 0; k < 16; ++k) {
        b[k] = (unsigned)d[k] / NPB;
        if (v[k]) atomicAdd(&lcnt[b[k]], 1);
    }
    __syncthreads();
    for (int i = t; i < NBUCK; i += 512) {
        int c = lcnt[i];
        lbase[i] = (c > 0) ? atomicAdd(&meta[i], c) : 0;
    }
    __syncthreads();
#pragma unroll
    for (int k = 0; k < 16; ++k) {
        if (!v[k]) continue;
        int slot = atomicAdd(&lidx[b[k]], 1);
        int pos = lbase[b[k]] + slot;
        if (pos < capB) {
            int local = d[k] - b[k] * NPB;
            buckets[(size_t)b[k] * capB + pos] = (local << 17) | s[k];
        } else {  // statistically unreachable
            int oi = atomicAdd(&meta[NBUCK], 1);
            ovfA[(size_t)oi * 2] = s[k];
            ovfA[(size_t)oi * 2 + 1] = d[k];
        }
    }
}

// ---- pass B: one block per bucket; build src-range-partitioned ELL rows
//      in LDS (lo from front, hi from back), stream out. ----
__global__ __launch_bounds__(256) void k_fill_lds(const int* __restrict__ buckets,
                                                  int capB,
                                                  const int* __restrict__ meta_ro,
                                                  const int* __restrict__ ovfA,
                                                  int* __restrict__ deg,
                                                  int* __restrict__ ell, int N,
                                                  int half) {
    __shared__ int clo_[NPB];
    __shared__ int chi_[NPB];
    __shared__ int ells[NPB * WI];  // 200*64*4 = 51200 B
    const int t = threadIdx.x;
    const int b = blockIdx.x;
    const int base = b * NPB;
    for (int i = t; i < NPB; i += 256) { clo_[i] = 0; chi_[i] = 0; }
    __syncthreads();
    const int cnt = min(meta_ro[b], capB);
    const int* bk = buckets + (size_t)b * capB;
    for (int i = t; i < cnt; i += 256) {
        unsigned v = (unsigned)__builtin_nontemporal_load(bk + i);
        int s = (int)(v & 0x1FFFFu);
        int local = (int)(v >> 17);
        if (s < half) {
            int slot = atomicAdd(&clo_[local], 1);
            if (slot < WI) ells[local * WI + slot] = s;
        } else {
            int pos = atomicAdd(&chi_[local], 1);
            if (pos < WI) ells[local * WI + (WI - 1 - pos)] = s;
        }
    }
    // pass-A overflow edges in this block's range (normally zero)
    const int no = meta_ro[NBUCK];
    for (int i = t; i < no; i += 256) {
        int s = ovfA[(size_t)i * 2];
        int d = ovfA[(size_t)i * 2 + 1];
        if (d >= base && d < base + NPB) {
            int local = d - base;
            if (s < half) {
                int slot = atomicAdd(&clo_[local], 1);
                if (slot < WI) ells[local * WI + slot] = s;
            } else {
                int pos = atomicAdd(&chi_[local], 1);
                if (pos < WI) ells[local * WI + (WI - 1 - pos)] = s;
            }
        }
    }
    __syncthreads();
    const int nn = min(NPB, N - base);
    if (nn <= 0) return;
    for (int i = t; i < nn; i += 256) {
        int lo = clo_[i], hi = chi_[i];
        int dt = lo + hi;
        int l2 = min(lo, WI);
        int h2 = min(hi, WI - l2);
        deg[base + i] = l2 | (h2 << 8) | (min(dt, 65535) << 16);
    }
    const int lim = nn * WI;
    for (int j = t * 4; j < lim; j += 256 * 4) {
        const int row = j >> 6;
        const int jo = j & 63;
        const int lo = min(clo_[row], WI);
        const int hs = WI - min(chi_[row], WI - lo);
        if (jo < lo || jo + 4 > hs) {
            i32x4 vv = *(const i32x4*)&ells[j];
            __builtin_nontemporal_store(vv, (i32x4*)(ell + (size_t)base * WI + j));
        }
    }
}

// ---- mean aggregation: 1 node per 16-lane group, 16 nodes/block ----
// sweeps lo range [0,clo) then hi range [WI-chi,WI); out bf16; opt bf16 addend.
__global__ __launch_bounds__(256) void k_agg_q(const unsigned int* __restrict__ featq,
                                               const int* __restrict__ deg,
                                               const int* __restrict__ ell,
                                               unsigned short* __restrict__ outb,
                                               const unsigned short* __restrict__ addend,
                                               int n) {
    const int node = blockIdx.x * 16 + (threadIdx.x >> 4);
    const int l = threadIdx.x & 15;
    if (node >= n) return;
    const int dw = deg[node];
    const int clo = dw & 255;
    const int chi = (dw >> 8) & 255;
    const int dt = dw >> 16;
    const int* row = ell + (size_t)node * WI;
    f32x2 lo = {0.f, 0.f}, hi = {0.f, 0.f};
    if (clo > 0) sweep_fp8(featq, row, 0, clo, l, lo, hi);
    if (chi > 0) sweep_fp8(featq, row, WI - chi, WI, l, lo, hi);
    const float inv = 1.0f / (float)max(dt, 1);
    float vx = lo.x * inv, vy = lo.y * inv, vz = hi.x * inv, vw = hi.y * inv;
    const size_t o = (size_t)node * 64 + l * 4;
    if (addend) {
        u16x4 ad = *(const u16x4*)(addend + o);
        vx += bf2f(ad[0]); vy += bf2f(ad[1]);
        vz += bf2f(ad[2]); vw += bf2f(ad[3]);
    }
    u16x4 ob;
    ob[0] = f2bf(vx); ob[1] = f2bf(vy); ob[2] = f2bf(vz); ob[3] = f2bf(vw);
    __builtin_nontemporal_store(ob, (u16x4*)(outb + o));
}

// ---- fused MFMA GEMM: h = relu([mean1b|xb]@W1+b1) in LDS;
//      pq(fp8) = h@Wl2 ; zbb(bf16) = h@Wr2+b2 ----
__global__ __launch_bounds__(256) void k_gemm_fused(
    const unsigned short* __restrict__ mean1b,  // [M][64]
    const unsigned short* __restrict__ xb,      // [M][64]
    const unsigned short* __restrict__ w1t,     // [128][128] bf16 [n][k]
    const unsigned short* __restrict__ w2t,     // [128][128] bf16 [n][k]
    const float* __restrict__ b1,
    const float* __restrict__ b2,
    unsigned int* __restrict__ pq,              // [M][16] u32 (64 fp8)
    unsigned short* __restrict__ zbb, int M) {  // [M][64] bf16
    __shared__ unsigned short W1s[128 * 128];
    __shared__ unsigned short W2s[128 * 128];
    __shared__ __align__(16) unsigned short HT[128 * 136];  // h tile, pad 8
    const int t = threadIdx.x;
    const int wv = t >> 6, l = t & 63;
    const int lr = l & 15, lq = l >> 4;
    const int wrow = wv * 32;
    const int row0 = blockIdx.x * 128 + wrow;

    const s16x8 zf = {0, 0, 0, 0, 0, 0, 0, 0};
    s16x8 af[2][4];
#pragma unroll
    for (int mt = 0; mt < 2; ++mt) {
        int r = row0 + mt * 16 + lr;
        bool ok = r < M;
#pragma unroll
        for (int ks = 0; ks < 4; ++ks) {
            int k = ks * 32 + lq * 8;
            const unsigned short* src = (k < 64) ? (mean1b + (size_t)r * 64 + k)
                                                 : (xb + (size_t)r * 64 + (k - 64));
            af[mt][ks] = ok ? *(const s16x8*)src : zf;
        }
    }
#pragma unroll
    for (int i = 0; i < 8; ++i) {
        int byte = (i * 256 + t) * 16;
        int swz = byte ^ (((byte >> 8) & 7) << 4);
        *(u16x8*)((char*)W1s + swz) = *(const u16x8*)((const char*)w1t + byte);
        *(u16x8*)((char*)W2s + swz) = *(const u16x8*)((const char*)w2t + byte);
    }
    __syncthreads();
    if (row0 >= M) return;

    // ---- layer 1 MFMA ----
    f32x4 acc[2][8];
#pragma unroll
    for (int mt = 0; mt < 2; ++mt)
#pragma unroll
        for (int nt = 0; nt < 8; ++nt) {
            f32x4 z = {0.f, 0.f, 0.f, 0.f};
            acc[mt][nt] = z;
        }
#pragma unroll
    for (int nt = 0; nt < 8; ++nt) {
        int n = nt * 16 + lr;
#pragma unroll
        for (int ks = 0; ks < 4; ++ks) {
            int byte = (n * 256 + ks * 64 + lq * 16) ^ ((n & 7) << 4);
            s16x8 bf = *(const s16x8*)((const char*)W1s + byte);
            acc[0][nt] = __builtin_amdgcn_mfma_f32_16x16x32_bf16(af[0][ks], bf, acc[0][nt], 0, 0, 0);
            acc[1][nt] = __builtin_amdgcn_mfma_f32_16x16x32_bf16(af[1][ks], bf, acc[1][nt], 0, 0, 0);
        }
    }
#pragma unroll
    for (int nt = 0; nt < 8; ++nt) {
        float bb = b1[nt * 16 + lr];
#pragma unroll
        for (int mt = 0; mt < 2; ++mt)
#pragma unroll
            for (int j = 0; j < 4; ++j) {
                float v = fmaxf(acc[mt][nt][j] + bb, 0.f);
                HT[(wrow + mt * 16 + lq * 4 + j) * 136 + nt * 16 + lr] = f2bf(v);
            }
    }
    // ---- layer 2 (A from own HT rows; no barrier needed) ----
    s16x8 af2[2][4];
#pragma unroll
    for (int mt = 0; mt < 2; ++mt)
#pragma unroll
        for (int ks = 0; ks < 4; ++ks)
            af2[mt][ks] = *(const s16x8*)&HT[(wrow + mt * 16 + lr) * 136 + ks * 32 + lq * 8];

    f32x4 acc2[2][8];
#pragma unroll
    for (int mt = 0; mt < 2; ++mt)
#pragma unroll
        for (int nt = 0; nt < 8; ++nt) {
            f32x4 z = {0.f, 0.f, 0.f, 0.f};
            acc2[mt][nt] = z;
        }
#pragma unroll
    for (int nt = 0; nt < 8; ++nt) {
        int n = nt * 16 + lr;
#pragma unroll
        for (int ks = 0; ks < 4; ++ks) {
            int byte = (n * 256 + ks * 64 + lq * 16) ^ ((n & 7) << 4);
            s16x8 bf = *(const s16x8*)((const char*)W2s + byte);
            acc2[0][nt] = __builtin_amdgcn_mfma_f32_16x16x32_bf16(af2[0][ks], bf, acc2[0][nt], 0, 0, 0);
            acc2[1][nt] = __builtin_amdgcn_mfma_f32_16x16x32_bf16(af2[1][ks], bf, acc2[1][nt], 0, 0, 0);
        }
    }
    char* scratch = (char*)&HT[(size_t)wrow * 136];  // 8704 B, wave-private
    // epilogue A: pq (cols 0..63 -> fp8) via byte stage [32][68]
    unsigned char* csb = (unsigned char*)scratch;
#pragma unroll
    for (int nt = 0; nt < 4; ++nt)
#pragma unroll
        for (int mt = 0; mt < 2; ++mt)
#pragma unroll
            for (int j = 0; j < 4; ++j)
                csb[(mt * 16 + lq * 4 + j) * 68 + nt * 16 + lr] = one_fp8(acc2[mt][nt][j]);
#pragma unroll
    for (int p = 0; p < 8; ++p) {
        int r = p * 4 + lq;
        int gr = row0 + r;
        if (gr < M) {
            unsigned int v = *(const unsigned int*)&csb[r * 68 + lr * 4];
            __builtin_nontemporal_store(v, pq + (size_t)gr * 16 + lr);
        }
    }
    __syncthreads();
    // epilogue B: zbb (cols 64..127 -> bf16, +b2) via u16 stage [32][72]
    unsigned short* csu = (unsigned short*)scratch;
#pragma unroll
    for (int nt = 4; nt < 8; ++nt) {
        int col = (nt - 4) * 16 + lr;
        float bb = b2[col];
#pragma unroll
        for (int mt = 0; mt < 2; ++mt)
#pragma unroll
            for (int j = 0; j < 4; ++j)
                csu[(mt * 16 + lq * 4 + j) * 72 + col] = f2bf(acc2[mt][nt][j] + bb);
    }
#pragma unroll
    for (int p = 0; p < 8; ++p) {
        int r = p * 4 + lq;
        int gr = row0 + r;
        if (gr < M) {
            u16x4 v = *(const u16x4*)&csu[r * 72 + lr * 4];
            __builtin_nontemporal_store(v, (u16x4*)(zbb + (size_t)gr * 64 + lr * 4));
        }
    }
}

// ---- decode over bf16 z: 16 lanes per pair; u16x4 loads; shfl reduce ----
__global__ __launch_bounds__(256) void k_decode(const unsigned short* __restrict__ zq,
                                                const int* __restrict__ eli,
                                                float* __restrict__ out, int P) {
    int t = threadIdx.x;
    int g = blockIdx.x * 16 + (t >> 4);
    int l = t & 15;
    if (g >= P) return;
    int a = __builtin_nontemporal_load(eli + g);
    int b = __builtin_nontemporal_load(eli + P + g);
    u16x4 va = *(const u16x4*)(zq + (size_t)a * 64 + l * 4);
    u16x4 vb = *(const u16x4*)(zq + (size_t)b * 64 + l * 4);
    float s = bf2f(va[0]) * bf2f(vb[0]) + bf2f(va[1]) * bf2f(vb[1])
            + bf2f(va[2]) * bf2f(vb[2]) + bf2f(va[3]) * bf2f(vb[3]);
    s += __shfl_xor(s, 1);
    s += __shfl_xor(s, 2);
    s += __shfl_xor(s, 4);
    s += __shfl_xor(s, 8);
    if (l == 0) out[g] = s;
}

extern "C" void kernel_launch(void* const* d_in, const int* in_sizes, int n_in,
                              void* d_out, int out_size, void* d_ws, size_t ws_size,
                              hipStream_t stream) {
    const float* x   = (const float*)d_in[0];
    const float* Wl1 = (const float*)d_in[1];
    const float* Wr1 = (const float*)d_in[2];
    const float* b1  = (const float*)d_in[3];
    const float* Wl2 = (const float*)d_in[4];
    const float* Wr2 = (const float*)d_in[5];
    const float* b2  = (const float*)d_in[6];
    const int* ei  = (const int*)d_in[7];
    const int* eli = (const int*)d_in[8];
    const int N = in_sizes[0] / 64;
    const int E = in_sizes[7] / 2;
    const int P = in_sizes[8] / 2;
    float* out = (float*)d_out;

    const int capB = ((E / NBUCK) * 5 / 4 + 1024 + 3) & ~3;
    const int half = N / 2;

    char* w = (char*)d_ws;
    auto alloc = [&](size_t bytes) {
        char* pp = w;
        w += (bytes + 255) & ~(size_t)255;
        return pp;
    };
    int* deg  = (int*)alloc((size_t)N * 4);
    int* meta = (int*)alloc(4096);
    int* ell  = (int*)alloc((size_t)N * WI * 4);
    unsigned short* xb     = (unsigned short*)alloc((size_t)N * 64 * 2);
    unsigned int*   xq     = (unsigned int*)alloc((size_t)N * 64);
    unsigned int*   pq     = (unsigned int*)alloc((size_t)N * 64);
    unsigned short* mean1b = (unsigned short*)alloc((size_t)N * 64 * 2);
    unsigned short* zq     = (unsigned short*)alloc((size_t)N * 64 * 2);
    unsigned short* zbb    = (unsigned short*)alloc((size_t)N * 64 * 2);
    unsigned short* w1t    = (unsigned short*)alloc(128 * 128 * 2);
    unsigned short* w2t    = (unsigned short*)alloc(128 * 128 * 2);
    int* buckets = (int*)alloc((size_t)NBUCK * capB * 4);
    int* ovfA    = (int*)alloc((size_t)E * 8);

    {
        long long n = (long long)N * 64;
        int xblocks = (int)((n / 8 + 255) / 256);
        k_prep<<<16 + xblocks, 256, 0, stream>>>(x, Wl1, Wr1, Wl2, Wr2,
                                                 w1t, w2t, xb, xq, meta, n);
    }

    k_bucket<<<(E + 8191) / 8192, 512, 0, stream>>>(ei, E, capB, buckets, meta, ovfA);
    k_fill_lds<<<(N + NPB - 1) / NPB, 256, 0, stream>>>(buckets, capB, meta, ovfA,
                                                        deg, ell, N, half);

    const int agg_grid = (N + 15) / 16;
    k_agg_q<<<agg_grid, 256, 0, stream>>>(xq, deg, ell, mean1b, nullptr, N);

    const int gemm_grid = (N + 127) / 128;
    k_gemm_fused<<<gemm_grid, 256, 0, stream>>>(mean1b, xb, w1t, w2t, b1, b2,
                                                pq, zbb, N);

    k_agg_q<<<agg_grid, 256, 0, stream>>>(pq, deg, ell, zq, zbb, N);

    k_decode<<<(P + 15) / 16, 256, 0, stream>>>(zq, eli, out, P);
}

// Round 16
// 149.297 us; speedup vs baseline: 1.4467x; 1.0723x over previous
//
#include <hip/hip_runtime.h>
#include <hip/hip_bf16.h>

// GNN link predictor: 2x SAGEConv(mean) + dot-product decode.
// Round 16 (= round 12 exact + 512-thread k_bucket):
//   - ELL pull aggregation over fp8 rows (64B), 8-deep unroll, packed cvt.
//     Measured: agg time invariant to FETCH (54-88MB) -> bound by random
//     64B-granule transaction rate (~1.6M line txns/pass ~= 40us).
//   - fused MFMA GEMM (h in LDS); outputs pq(fp8) + zbb(bf16).
//   - agg2 adds bf16 zbb addend, writes bf16 zq for decode.
//   - 512-bucket two-pass ELL build; ovfA folded into fill_lds.

#define NBUCK 512
#define NPB   200   // nodes per bucket
#define WI    64    // ELL width
// meta: [0..NBUCK) bucket cursors; [NBUCK] ovfA count

typedef __attribute__((ext_vector_type(2))) float f32x2;
typedef __attribute__((ext_vector_type(4))) float f32x4;
typedef __attribute__((ext_vector_type(4))) int i32x4;
typedef __attribute__((ext_vector_type(2))) unsigned int u32x2;
typedef __attribute__((ext_vector_type(4))) unsigned short u16x4;
typedef __attribute__((ext_vector_type(8))) unsigned short u16x8;
typedef __attribute__((ext_vector_type(8))) short s16x8;   // bf16 MFMA frag

__device__ inline unsigned short f2bf(float f) {
    unsigned u = __float_as_uint(f);
    u += 0x7fffu + ((u >> 16) & 1u);
    return (unsigned short)(u >> 16);
}
__device__ inline float bf2f(unsigned short h) {
    return __uint_as_float(((unsigned)h) << 16);
}
__device__ inline unsigned int pk4_fp8(float a, float b, float c, float d) {
    int w = __builtin_amdgcn_cvt_pk_fp8_f32(a, b, 0, false);
    w = __builtin_amdgcn_cvt_pk_fp8_f32(c, d, w, true);
    return (unsigned int)w;
}
__device__ inline unsigned char one_fp8(float a) {
    return (unsigned char)(__builtin_amdgcn_cvt_pk_fp8_f32(a, a, 0, false) & 0xFF);
}
__device__ inline void acc_fp8(unsigned int a, f32x2& lo, f32x2& hi) {
#if __has_builtin(__builtin_amdgcn_cvt_pk_f32_fp8)
    lo += __builtin_amdgcn_cvt_pk_f32_fp8((int)a, false);
    hi += __builtin_amdgcn_cvt_pk_f32_fp8((int)a, true);
#else
    lo.x += __builtin_amdgcn_cvt_f32_fp8((int)a, 0);
    lo.y += __builtin_amdgcn_cvt_f32_fp8((int)a, 1);
    hi.x += __builtin_amdgcn_cvt_f32_fp8((int)a, 2);
    hi.y += __builtin_amdgcn_cvt_f32_fp8((int)a, 3);
#endif
}

// ---- prep: weights -> bf16 [n][k]; x -> bf16 + fp8; zero meta ----
__global__ __launch_bounds__(256) void k_prep(const float* __restrict__ x,
                                              const float* __restrict__ Wl1,
                                              const float* __restrict__ Wr1,
                                              const float* __restrict__ Wl2,
                                              const float* __restrict__ Wr2,
                                              unsigned short* __restrict__ w1t,
                                              unsigned short* __restrict__ w2t,
                                              unsigned short* __restrict__ xb,
                                              unsigned int* __restrict__ xq,
                                              int* __restrict__ meta,
                                              long long nx) {
    if (blockIdx.x < 16) {  // weights: 2 x 128x128 (+ meta zero in block 0)
        if (blockIdx.x == 0) {
            i32x4 z = {0, 0, 0, 0};
            *(i32x4*)(meta + threadIdx.x * 4) = z;
        }
        int id = (blockIdx.x * 256 + threadIdx.x) * 8;  // 0..32760
        int which = id >> 14;
        int r0 = id & 16383;
#pragma unroll
        for (int i = 0; i < 8; ++i) {
            int r = r0 + i;
            int n = r >> 7, k = r & 127;
            float v;
            if (which == 0) v = (k < 64) ? Wl1[k * 128 + n] : Wr1[(k - 64) * 128 + n];
            else            v = (n < 64) ? Wl2[k * 64 + n] : Wr2[k * 64 + (n - 64)];
            (which ? w2t : w1t)[r] = f2bf(v);
        }
        return;
    }
    long long i = ((long long)(blockIdx.x - 16) * 256 + threadIdx.x) * 8;
    if (i + 8 > nx) return;
    f32x4 a = __builtin_nontemporal_load((const f32x4*)(x + i));
    f32x4 b = __builtin_nontemporal_load((const f32x4*)(x + i + 4));
    u16x8 o;
    o[0] = f2bf(a.x); o[1] = f2bf(a.y); o[2] = f2bf(a.z); o[3] = f2bf(a.w);
    o[4] = f2bf(b.x); o[5] = f2bf(b.y); o[6] = f2bf(b.z); o[7] = f2bf(b.w);
    __builtin_nontemporal_store(o, (u16x8*)(xb + i));
    u32x2 q;
    q.x = pk4_fp8(a.x, a.y, a.z, a.w);
    q.y = pk4_fp8(b.x, b.y, b.z, b.w);
    __builtin_nontemporal_store(q, (u32x2*)(xq + (i >> 2)));
}

// ---- pass A: edges -> 512 dst-range buckets (packed 4B: local<<17 | src) ----
// 512 threads x 16 edges = 8192-edge tiles (64B avg bucket runs).
__global__ __launch_bounds__(512) void k_bucket(const int* __restrict__ ei, int E,
                                                int capB,
                                                int* __restrict__ buckets,
                                                int* __restrict__ meta,
                                                int* __restrict__ ovfA) {
    __shared__ int lcnt[NBUCK];
    __shared__ int lbase[NBUCK];
    __shared__ int lidx[NBUCK];
    const int t = threadIdx.x;
    const int e0 = blockIdx.x * 8192;
    for (int i = t; i < NBUCK; i += 512) { lcnt[i] = 0; lidx[i] = 0; }
    __syncthreads();

    int s[16], d[16], b[16];
    bool v[16];
#pragma unroll
    for (int r = 0; r < 4; ++r) {
        int e = e0 + r * 2048 + t * 4;
        i32x4 s4, d4;
        if (e + 4 <= E) {
            s4 = __builtin_nontemporal_load((const i32x4*)(ei + e));
            d4 = __builtin_nontemporal_load((const i32x4*)(ei + E + e));
        } else {
            s4.x = (e < E) ? ei[e] : 0;         d4.x = (e < E) ? ei[E + e] : 0;
            s4.y = (e + 1 < E) ? ei[e + 1] : 0; d4.y = (e + 1 < E) ? ei[E + e + 1] : 0;
            s4.z = (e + 2 < E) ? ei[e + 2] : 0; d4.z = (e + 2 < E) ? ei[E + e + 2] : 0;
            s4.w = (e + 3 < E) ? ei[e + 3] : 0; d4.w = (e + 3 < E) ? ei[E + e + 3] : 0;
        }
        s[r * 4 + 0] = s4.x; s[r * 4 + 1] = s4.y; s[r * 4 + 2] = s4.z; s[r * 4 + 3] = s4.w;
        d[r * 4 + 0] = d4.x; d[r * 4 + 1] = d4.y; d[r * 4 + 2] = d4.z; d[r * 4 + 3] = d4.w;
        v[r * 4 + 0] = (e < E); v[r * 4 + 1] = (e + 1 < E);
        v[r * 4 + 2] = (e + 2 < E); v[r * 4 + 3] = (e + 3 < E);
    }
#pragma unroll
    for (int k = 0; k < 16; ++k) {
        b[k] = (unsigned)d[k] / NPB;
        if (v[k]) atomicAdd(&lcnt[b[k]], 1);
    }
    __syncthreads();
    for (int i = t; i < NBUCK; i += 512) {
        int c = lcnt[i];
        lbase[i] = (c > 0) ? atomicAdd(&meta[i], c) : 0;
    }
    __syncthreads();
#pragma unroll
    for (int k = 0; k < 16; ++k) {
        if (!v[k]) continue;
        int slot = atomicAdd(&lidx[b[k]], 1);
        int pos = lbase[b[k]] + slot;
        if (pos < capB) {
            int local = d[k] - b[k] * NPB;
            buckets[(size_t)b[k] * capB + pos] = (local << 17) | s[k];
        } else {  // statistically unreachable
            int oi = atomicAdd(&meta[NBUCK], 1);
            ovfA[(size_t)oi * 2] = s[k];
            ovfA[(size_t)oi * 2 + 1] = d[k];
        }
    }
}

// ---- pass B: one block per bucket; build ELL slab in LDS, stream out ----
// also folds in pass-A overflow edges (normally zero).
__global__ __launch_bounds__(256) void k_fill_lds(const int* __restrict__ buckets,
                                                  int capB,
                                                  const int* __restrict__ meta_ro,
                                                  const int* __restrict__ ovfA,
                                                  int* __restrict__ deg,
                                                  int* __restrict__ ell, int N) {
    __shared__ int cur[NPB];
    __shared__ int ells[NPB * WI];  // 200*64*4 = 51200 B
    const int t = threadIdx.x;
    const int b = blockIdx.x;
    const int base = b * NPB;
    for (int i = t; i < NPB; i += 256) cur[i] = 0;
    __syncthreads();
    const int cnt = min(meta_ro[b], capB);
    const int* bk = buckets + (size_t)b * capB;
    for (int i = t; i < cnt; i += 256) {
        unsigned v = (unsigned)__builtin_nontemporal_load(bk + i);
        int s = (int)(v & 0x1FFFFu);
        int local = (int)(v >> 17);
        int slot = atomicAdd(&cur[local], 1);
        if (slot < WI) ells[local * WI + slot] = s;   // deg>WI: drop (P~1e-19)
    }
    // pass-A overflow edges in this block's range (normally zero)
    const int no = meta_ro[NBUCK];
    for (int i = t; i < no; i += 256) {
        int s = ovfA[(size_t)i * 2];
        int d = ovfA[(size_t)i * 2 + 1];
        if (d >= base && d < base + NPB) {
            int slot = atomicAdd(&cur[d - base], 1);
            if (slot < WI) ells[(d - base) * WI + slot] = s;
        }
    }
    __syncthreads();
    const int nn = min(NPB, N - base);
    if (nn <= 0) return;
    for (int i = t; i < nn; i += 256) deg[base + i] = cur[i];
    const int lim = nn * WI;
    for (int j = t * 4; j < lim; j += 256 * 4) {
        if ((j & (WI - 1)) >= cur[j >> 6]) continue;  // row tail: never read
        i32x4 vv = *(const i32x4*)&ells[j];
        __builtin_nontemporal_store(vv, (i32x4*)(ell + (size_t)base * WI + j));
    }
}

// ---- mean aggregation over fp8 rows (64B); 16 lanes x 4ch per node ----
// 8-deep gather unroll; packed fp8->f32 cvt; out bf16; optional bf16 addend.
__global__ __launch_bounds__(256) void k_agg_q(const unsigned int* __restrict__ featq,
                                               const int* __restrict__ deg,
                                               const int* __restrict__ ell,
                                               unsigned short* __restrict__ outb,
                                               const unsigned short* __restrict__ addend,
                                               int n) {
    const int node = blockIdx.x * 16 + (threadIdx.x >> 4);
    const int l = threadIdx.x & 15;
    if (node >= n) return;
    const int dg = deg[node];
    const int cnt = min(dg, WI);
    const int* row = ell + (size_t)node * WI;
    f32x2 lo = {0.f, 0.f}, hi = {0.f, 0.f};
    int j = 0;
    for (; j + 8 <= cnt; j += 8) {
        i32x4 sA = __builtin_nontemporal_load((const i32x4*)(row + j));
        i32x4 sB = __builtin_nontemporal_load((const i32x4*)(row + j + 4));
        unsigned a0 = featq[(size_t)sA.x * 16 + l];
        unsigned a1 = featq[(size_t)sA.y * 16 + l];
        unsigned a2 = featq[(size_t)sA.z * 16 + l];
        unsigned a3 = featq[(size_t)sA.w * 16 + l];
        unsigned a4 = featq[(size_t)sB.x * 16 + l];
        unsigned a5 = featq[(size_t)sB.y * 16 + l];
        unsigned a6 = featq[(size_t)sB.z * 16 + l];
        unsigned a7 = featq[(size_t)sB.w * 16 + l];
        acc_fp8(a0, lo, hi); acc_fp8(a1, lo, hi);
        acc_fp8(a2, lo, hi); acc_fp8(a3, lo, hi);
        acc_fp8(a4, lo, hi); acc_fp8(a5, lo, hi);
        acc_fp8(a6, lo, hi); acc_fp8(a7, lo, hi);
    }
    if (j + 4 <= cnt) {
        i32x4 sA = __builtin_nontemporal_load((const i32x4*)(row + j));
        unsigned a0 = featq[(size_t)sA.x * 16 + l];
        unsigned a1 = featq[(size_t)sA.y * 16 + l];
        unsigned a2 = featq[(size_t)sA.z * 16 + l];
        unsigned a3 = featq[(size_t)sA.w * 16 + l];
        acc_fp8(a0, lo, hi); acc_fp8(a1, lo, hi);
        acc_fp8(a2, lo, hi); acc_fp8(a3, lo, hi);
        j += 4;
    }
    for (; j < cnt; ++j) {
        int s = __builtin_nontemporal_load(row + j);
        acc_fp8(featq[(size_t)s * 16 + l], lo, hi);
    }
    const float inv = 1.0f / (float)max(dg, 1);
    float vx = lo.x * inv, vy = lo.y * inv, vz = hi.x * inv, vw = hi.y * inv;
    const size_t o = (size_t)node * 64 + l * 4;
    if (addend) {
        u16x4 ad = *(const u16x4*)(addend + o);
        vx += bf2f(ad[0]); vy += bf2f(ad[1]);
        vz += bf2f(ad[2]); vw += bf2f(ad[3]);
    }
    u16x4 ob;
    ob[0] = f2bf(vx); ob[1] = f2bf(vy); ob[2] = f2bf(vz); ob[3] = f2bf(vw);
    __builtin_nontemporal_store(ob, (u16x4*)(outb + o));
}

// ---- fused MFMA GEMM: h = relu([mean1b|xb]@W1+b1) in LDS;
//      pq(fp8) = h@Wl2 ; zbb(bf16) = h@Wr2+b2 ----
__global__ __launch_bounds__(256) void k_gemm_fused(
    const unsigned short* __restrict__ mean1b,  // [M][64]
    const unsigned short* __restrict__ xb,      // [M][64]
    const unsigned short* __restrict__ w1t,     // [128][128] bf16 [n][k]
    const unsigned short* __restrict__ w2t,     // [128][128] bf16 [n][k]
    const float* __restrict__ b1,
    const float* __restrict__ b2,
    unsigned int* __restrict__ pq,              // [M][16] u32 (64 fp8)
    unsigned short* __restrict__ zbb, int M) {  // [M][64] bf16
    __shared__ unsigned short W1s[128 * 128];
    __shared__ unsigned short W2s[128 * 128];
    __shared__ __align__(16) unsigned short HT[128 * 136];  // h tile, pad 8
    const int t = threadIdx.x;
    const int wv = t >> 6, l = t & 63;
    const int lr = l & 15, lq = l >> 4;
    const int wrow = wv * 32;
    const int row0 = blockIdx.x * 128 + wrow;

    const s16x8 zf = {0, 0, 0, 0, 0, 0, 0, 0};
    s16x8 af[2][4];
#pragma unroll
    for (int mt = 0; mt < 2; ++mt) {
        int r = row0 + mt * 16 + lr;
        bool ok = r < M;
#pragma unroll
        for (int ks = 0; ks < 4; ++ks) {
            int k = ks * 32 + lq * 8;
            const unsigned short* src = (k < 64) ? (mean1b + (size_t)r * 64 + k)
                                                 : (xb + (size_t)r * 64 + (k - 64));
            af[mt][ks] = ok ? *(const s16x8*)src : zf;
        }
    }
#pragma unroll
    for (int i = 0; i < 8; ++i) {
        int byte = (i * 256 + t) * 16;
        int swz = byte ^ (((byte >> 8) & 7) << 4);
        *(u16x8*)((char*)W1s + swz) = *(const u16x8*)((const char*)w1t + byte);
        *(u16x8*)((char*)W2s + swz) = *(const u16x8*)((const char*)w2t + byte);
    }
    __syncthreads();
    if (row0 >= M) return;

    // ---- layer 1 MFMA ----
    f32x4 acc[2][8];
#pragma unroll
    for (int mt = 0; mt < 2; ++mt)
#pragma unroll
        for (int nt = 0; nt < 8; ++nt) {
            f32x4 z = {0.f, 0.f, 0.f, 0.f};
            acc[mt][nt] = z;
        }
#pragma unroll
    for (int nt = 0; nt < 8; ++nt) {
        int n = nt * 16 + lr;
#pragma unroll
        for (int ks = 0; ks < 4; ++ks) {
            int byte = (n * 256 + ks * 64 + lq * 16) ^ ((n & 7) << 4);
            s16x8 bf = *(const s16x8*)((const char*)W1s + byte);
            acc[0][nt] = __builtin_amdgcn_mfma_f32_16x16x32_bf16(af[0][ks], bf, acc[0][nt], 0, 0, 0);
            acc[1][nt] = __builtin_amdgcn_mfma_f32_16x16x32_bf16(af[1][ks], bf, acc[1][nt], 0, 0, 0);
        }
    }
#pragma unroll
    for (int nt = 0; nt < 8; ++nt) {
        float bb = b1[nt * 16 + lr];
#pragma unroll
        for (int mt = 0; mt < 2; ++mt)
#pragma unroll
            for (int j = 0; j < 4; ++j) {
                float v = fmaxf(acc[mt][nt][j] + bb, 0.f);
                HT[(wrow + mt * 16 + lq * 4 + j) * 136 + nt * 16 + lr] = f2bf(v);
            }
    }
    // ---- layer 2 (A from own HT rows; no barrier needed) ----
    s16x8 af2[2][4];
#pragma unroll
    for (int mt = 0; mt < 2; ++mt)
#pragma unroll
        for (int ks = 0; ks < 4; ++ks)
            af2[mt][ks] = *(const s16x8*)&HT[(wrow + mt * 16 + lr) * 136 + ks * 32 + lq * 8];

    f32x4 acc2[2][8];
#pragma unroll
    for (int mt = 0; mt < 2; ++mt)
#pragma unroll
        for (int nt = 0; nt < 8; ++nt) {
            f32x4 z = {0.f, 0.f, 0.f, 0.f};
            acc2[mt][nt] = z;
        }
#pragma unroll
    for (int nt = 0; nt < 8; ++nt) {
        int n = nt * 16 + lr;
#pragma unroll
        for (int ks = 0; ks < 4; ++ks) {
            int byte = (n * 256 + ks * 64 + lq * 16) ^ ((n & 7) << 4);
            s16x8 bf = *(const s16x8*)((const char*)W2s + byte);
            acc2[0][nt] = __builtin_amdgcn_mfma_f32_16x16x32_bf16(af2[0][ks], bf, acc2[0][nt], 0, 0, 0);
            acc2[1][nt] = __builtin_amdgcn_mfma_f32_16x16x32_bf16(af2[1][ks], bf, acc2[1][nt], 0, 0, 0);
        }
    }
    char* scratch = (char*)&HT[(size_t)wrow * 136];  // 8704 B, wave-private
    // epilogue A: pq (cols 0..63 -> fp8) via byte stage [32][68]
    unsigned char* csb = (unsigned char*)scratch;
#pragma unroll
    for (int nt = 0; nt < 4; ++nt)
#pragma unroll
        for (int mt = 0; mt < 2; ++mt)
#pragma unroll
            for (int j = 0; j < 4; ++j)
                csb[(mt * 16 + lq * 4 + j) * 68 + nt * 16 + lr] = one_fp8(acc2[mt][nt][j]);
#pragma unroll
    for (int p = 0; p < 8; ++p) {
        int r = p * 4 + lq;
        int gr = row0 + r;
        if (gr < M) {
            unsigned int v = *(const unsigned int*)&csb[r * 68 + lr * 4];
            __builtin_nontemporal_store(v, pq + (size_t)gr * 16 + lr);
        }
    }
    __syncthreads();
    // epilogue B: zbb (cols 64..127 -> bf16, +b2) via u16 stage [32][72]
    unsigned short* csu = (unsigned short*)scratch;
#pragma unroll
    for (int nt = 4; nt < 8; ++nt) {
        int col = (nt - 4) * 16 + lr;
        float bb = b2[col];
#pragma unroll
        for (int mt = 0; mt < 2; ++mt)
#pragma unroll
            for (int j = 0; j < 4; ++j)
                csu[(mt * 16 + lq * 4 + j) * 72 + col] = f2bf(acc2[mt][nt][j] + bb);
    }
#pragma unroll
    for (int p = 0; p < 8; ++p) {
        int r = p * 4 + lq;
        int gr = row0 + r;
        if (gr < M) {
            u16x4 v = *(const u16x4*)&csu[r * 72 + lr * 4];
            __builtin_nontemporal_store(v, (u16x4*)(zbb + (size_t)gr * 64 + lr * 4));
        }
    }
}

// ---- decode over bf16 z: 16 lanes per pair; u16x4 loads; shfl reduce ----
__global__ __launch_bounds__(256) void k_decode(const unsigned short* __restrict__ zq,
                                                const int* __restrict__ eli,
                                                float* __restrict__ out, int P) {
    int t = threadIdx.x;
    int g = blockIdx.x * 16 + (t >> 4);
    int l = t & 15;
    if (g >= P) return;
    int a = __builtin_nontemporal_load(eli + g);
    int b = __builtin_nontemporal_load(eli + P + g);
    u16x4 va = *(const u16x4*)(zq + (size_t)a * 64 + l * 4);
    u16x4 vb = *(const u16x4*)(zq + (size_t)b * 64 + l * 4);
    float s = bf2f(va[0]) * bf2f(vb[0]) + bf2f(va[1]) * bf2f(vb[1])
            + bf2f(va[2]) * bf2f(vb[2]) + bf2f(va[3]) * bf2f(vb[3]);
    s += __shfl_xor(s, 1);
    s += __shfl_xor(s, 2);
    s += __shfl_xor(s, 4);
    s += __shfl_xor(s, 8);
    if (l == 0) out[g] = s;
}

extern "C" void kernel_launch(void* const* d_in, const int* in_sizes, int n_in,
                              void* d_out, int out_size, void* d_ws, size_t ws_size,
                              hipStream_t stream) {
    const float* x   = (const float*)d_in[0];
    const float* Wl1 = (const float*)d_in[1];
    const float* Wr1 = (const float*)d_in[2];
    const float* b1  = (const float*)d_in[3];
    const float* Wl2 = (const float*)d_in[4];
    const float* Wr2 = (const float*)d_in[5];
    const float* b2  = (const float*)d_in[6];
    const int* ei  = (const int*)d_in[7];
    const int* eli = (const int*)d_in[8];
    const int N = in_sizes[0] / 64;
    const int E = in_sizes[7] / 2;
    const int P = in_sizes[8] / 2;
    float* out = (float*)d_out;

    const int capB = ((E / NBUCK) * 5 / 4 + 1024 + 3) & ~3;

    char* w = (char*)d_ws;
    auto alloc = [&](size_t bytes) {
        char* pp = w;
        w += (bytes + 255) & ~(size_t)255;
        return pp;
    };
    int* deg  = (int*)alloc((size_t)N * 4);
    int* meta = (int*)alloc(4096);
    int* ell  = (int*)alloc((size_t)N * WI * 4);
    unsigned short* xb     = (unsigned short*)alloc((size_t)N * 64 * 2);
    unsigned int*   xq     = (unsigned int*)alloc((size_t)N * 64);
    unsigned int*   pq     = (unsigned int*)alloc((size_t)N * 64);
    unsigned short* mean1b = (unsigned short*)alloc((size_t)N * 64 * 2);
    unsigned short* zq     = (unsigned short*)alloc((size_t)N * 64 * 2);
    unsigned short* zbb    = (unsigned short*)alloc((size_t)N * 64 * 2);
    unsigned short* w1t    = (unsigned short*)alloc(128 * 128 * 2);
    unsigned short* w2t    = (unsigned short*)alloc(128 * 128 * 2);
    int* buckets = (int*)alloc((size_t)NBUCK * capB * 4);
    int* ovfA    = (int*)alloc((size_t)E * 8);

    {
        long long n = (long long)N * 64;
        int xblocks = (int)((n / 8 + 255) / 256);
        k_prep<<<16 + xblocks, 256, 0, stream>>>(x, Wl1, Wr1, Wl2, Wr2,
                                                 w1t, w2t, xb, xq, meta, n);
    }

    k_bucket<<<(E + 8191) / 8192, 512, 0, stream>>>(ei, E, capB, buckets, meta, ovfA);
    k_fill_lds<<<(N + NPB - 1) / NPB, 256, 0, stream>>>(buckets, capB, meta, ovfA,
                                                        deg, ell, N);

    const int agg_grid = (N + 15) / 16;
    k_agg_q<<<agg_grid, 256, 0, stream>>>(xq, deg, ell, mean1b, nullptr, N);

    const int gemm_grid = (N + 127) / 128;
    k_gemm_fused<<<gemm_grid, 256, 0, stream>>>(mean1b, xb, w1t, w2t, b1, b2,
                                                pq, zbb, N);

    k_agg_q<<<agg_grid, 256, 0, stream>>>(pq, deg, ell, zq, zbb, N);

    k_decode<<<(P + 15) / 16, 256, 0, stream>>>(zq, eli, out, P);
}